// Round 11
// baseline (388.292 us; speedup 1.0000x reference)
//
#include <hip/hip_runtime.h>

typedef _Float16 f16x8 __attribute__((ext_vector_type(8)));
typedef float    f32x4 __attribute__((ext_vector_type(4)));

constexpr int BATCH = 2048;
constexpr int SEQ   = 512;
constexpr int H     = 50;
constexpr int NB    = 8;     // batch per block -> 256 blocks = 1 per CU
constexpr int NT    = 896;   // 14 waves: 7 L0 + 7 L1
constexpr int D     = 4;     // h1 ring depth (slots)
constexpr int PP    = 512;   // panel halfs: 64 k-rows x 8 cols

__device__ __forceinline__ float fexp2(float x) { return __builtin_amdgcn_exp2f(x); }
__device__ __forceinline__ float frcp(float x)  { return __builtin_amdgcn_rcpf(x); }
__device__ __forceinline__ _Float16 f16hi(float w) { return (_Float16)w; }
__device__ __forceinline__ _Float16 f16lo(float w) {
    _Float16 h = (_Float16)w; return (_Float16)(w - (float)h);
}
// panel address (halfs) for value (k, c), k<64, c<8
__device__ __forceinline__ int caddr(int k, int c) {
    return ((k >> 3) * 64) + c * 8 + (k & 7);
}
union H2U { unsigned u; _Float16 h[2]; };

constexpr float K1 = 1.4426950408889634f;   // log2(e)
constexpr float K2 = 2.8853900817779268f;   // 2*log2(e)

// === r18: decoupled producer-consumer groups (no per-step s_barrier) ===
// Ledger r9-r17: 285 -> 284 cy-us across 9 variants; every phase-cut returns
// only its pro-rata share because ONE barrier group re-convoys all 13 waves
// every step. Dependency graph is one-way: L0 (h1 rec) never reads h2. So:
//   waves 0-6  = L0 group: h1 ring (D=4 slots, 1KB each) holds h1(j)+x(j+1);
//     per step: 2 ds_read_b128 (h1+x), 4 MFMA (2 tiles x 2 chunks), act
//     1 chain/lane (2 tiles x 4 units x 8 cols via broadcast-dup hi cols),
//     write h1 into slot s%D. Sync: own LDS counter cnt0 (7 signals/step);
//     back-pressure: cnt1 >= 7*(s-D+1) before overwriting a slot.
//   waves 7-13 = L1 group: reads h1(p) from ring + own h2 dbuf (4 reads),
//     8 MFMA (per tile: Wih1 2-chain + Whh1 2-chain, joined), act, write h2.
//     Sync: own cnt1; data-ready: cnt0 >= 7*(p+1).
// Tiles {wv, wv+7} per wave (tile 13 slot dead). x rides ring rows 50/51
// (hi/lo f16, prescaled weights in A rows 50/51 of both tiles) staged by
// wave 6's 8 spare lanes (its T1 is dead). Gate prescale (-K1/-K2), merged
// rcp act: identical math to r17 -> absmax unchanged.
// Sync mechanics: monotonic u32 counters in LDS; signal = lgkmcnt(0) +
// lane0 atomicAdd; wait = volatile spin + sched_barrier + memory clobber.
// Deadlock-free: single block (always resident); L1 waits only on L0-ahead,
// L0 waits only on L1 >= s-D+1 which is implied reachable (proof in notes).
// No s_barrier in the loops; one final __syncthreads before the FC.

__global__ __launch_bounds__(NT, 4) void lstm2_pc(
    const float* __restrict__ x,
    const float* __restrict__ Wih0, const float* __restrict__ Whh0,
    const float* __restrict__ bih0, const float* __restrict__ bhh0,
    const float* __restrict__ Wih1, const float* __restrict__ Whh1,
    const float* __restrict__ bih1, const float* __restrict__ bhh1,
    const float* __restrict__ fcW,  const float* __restrict__ fcb,
    float* __restrict__ out)
{
    __shared__ _Float16 sRing[D][PP];   // h1 ring, 4 KB
    __shared__ _Float16 sH2[2][PP];     // L1 h2 double-buffer, 2 KB
    __shared__ unsigned sXu[SEQ * NB];  // pre-split x (hi,lo), 16 KB
    __shared__ float    sH2f[H * NB];   // final h2
    __shared__ unsigned sCnt[2];        // [0]=cnt0 (L0), [1]=cnt1 (L1)

    const int t    = threadIdx.x;
    const int wave = t >> 6, lane = t & 63;
    const int quad = lane >> 4, nn = lane & 15;
    const int bbase = blockIdx.x * NB;

    for (int i = t; i < D * PP; i += NT) ((_Float16*)sRing)[i] = (_Float16)0.f;
    for (int i = t; i < 2 * PP; i += NT) ((_Float16*)sH2)[i]  = (_Float16)0.f;
    if (t < 2) sCnt[t] = 0;
    for (int i = t; i < NB * SEQ; i += NT) {
        const int b = i >> 9, s = i & (SEQ - 1);
        const float xv = x[(bbase + b) * SEQ + s];
        H2U p; p.h[0] = f16hi(xv); p.h[1] = f16lo(xv);
        sXu[s * NB + b] = p.u;
    }
    __syncthreads();
    if (t < NB)                         // x(0) into slot D-1 (read at s=0)
        ((unsigned*)sRing[D - 1])[193 + 4 * t] = sXu[t];
    __syncthreads();

    const bool isL1 = (wave >= 7);
    const int  wv   = isL1 ? wave - 7 : wave;
    const int  T0   = wv, T1 = wv + 7;      // T1==13 dead (wave 6 of each group)
    const int  selT = nn >> 3;              // lane's act tile: 0->T0, 1->T1
    const int  col  = nn & 7;               // batch
    const int  jjS  = (selT ? T1 : T0) * 4 + quad;
    const bool vOK  = (jjS < H);

    volatile unsigned* vc0 = &sCnt[0];
    volatile unsigned* vc1 = &sCnt[1];
    auto waitge = [](volatile unsigned* c, unsigned tgt) {
        while (*c < tgt) {}
        __builtin_amdgcn_sched_barrier(0);
        asm volatile("" ::: "memory");
    };

    // per-lane bias (both groups), prescaled, layer = group
    f32x4 biasA = {0,0,0,0}, biasB = {0,0,0,0};
    {
        const float* bi = isL1 ? bih1 : bih0;
        const float* bh = isL1 ? bhh1 : bhh0;
        #pragma unroll
        for (int r = 0; r < 4; ++r) {
            const float sc = (r == 2) ? -K2 : -K1;
            const int jqA = T0 * 4 + quad, jqB = T1 * 4 + quad;
            biasA[r] = (jqA < H) ? sc * (bi[r * H + jqA] + bh[r * H + jqA]) : 0.f;
            biasB[r] = (jqB < H) ? sc * (bi[r * H + jqB] + bh[r * H + jqB]) : 0.f;
        }
    }

    const int rbase = quad * 64 + col * 8;  // chunk0 frag base; chunk1 = +256
    const int wslot = caddr(jjS < H ? jjS : 0, col);

    if (!isL1) {
        // ---- L0 group: A = Whh0 (k<50) + x-weight rows 50/51, 2 tiles ----
        f16x8 aA[2][2];
        #pragma unroll
        for (int tt = 0; tt < 2; ++tt) {
            const int  m    = tt ? T1 : T0;
            const int  jr   = m * 4 + (nn >> 2);
            const int  gate = nn & 3;
            const bool rv   = (jr < H);
            const int  lrow = gate * H + jr;
            const float rsc = (gate == 2) ? -K2 : -K1;
            #pragma unroll
            for (int q = 0; q < 2; ++q) {
                #pragma unroll
                for (int j = 0; j < 8; ++j) {
                    const int k = q * 32 + quad * 8 + j;
                    _Float16 v = (_Float16)0.f;
                    if (rv) {
                        if      (k < 50)  v = (_Float16)(rsc * Whh0[lrow * H + k]);
                        else if (k == 50) v = f16hi(rsc * Wih0[lrow]);
                        else if (k == 51) v = f16lo(rsc * Wih0[lrow]);
                    }
                    aA[tt][q][j] = v;
                }
            }
        }
        const bool xst = (wv == 6) && (quad == 0) && (selT == 1);  // 8 lanes
        float c = 0.f;
        #pragma unroll 1
        for (int s = 0; s < SEQ; ++s) {
            waitge(vc0, 7u * (unsigned)s);
            if (s >= D) waitge(vc1, 7u * (unsigned)(s - D + 1));
            const _Float16* br = sRing[(s + D - 1) & (D - 1)];
            _Float16*       bw = sRing[s & (D - 1)];
            const f16x8 q0 = *(const f16x8*)&br[rbase];
            const f16x8 q1 = *(const f16x8*)&br[256 + rbase];
            f32x4 gA = biasA;
            gA = __builtin_amdgcn_mfma_f32_16x16x32_f16(aA[0][0], q0, gA, 0, 0, 0);
            gA = __builtin_amdgcn_mfma_f32_16x16x32_f16(aA[0][1], q1, gA, 0, 0, 0);
            f32x4 gB = biasB;
            gB = __builtin_amdgcn_mfma_f32_16x16x32_f16(aA[1][0], q0, gB, 0, 0, 0);
            gB = __builtin_amdgcn_mfma_f32_16x16x32_f16(aA[1][1], q1, gB, 0, 0, 0);
            float g[4];
            #pragma unroll
            for (int r = 0; r < 4; ++r) g[r] = selT ? gB[r] : gA[r];
            {   // act (merged-rcp, prescaled)
                float Ei = fexp2(g[0]);
                float Ef = fexp2(g[1]);
                float Eg = fexp2(-fabsf(g[2]));
                float Eo = fexp2(g[3]);
                float P  = (1.f + Ei) * (1.f + Eg);
                float F  = 1.f + Ef;
                float R  = frcp(P * F);
                float tn = copysignf((1.f - Eg) * F, -g[2]);
                c = fmaf(c, P, tn) * R;
                float Ec = fexp2(-fabsf(K2 * c));
                float h  = copysignf((1.f - Ec) * frcp((1.f + Eo) * (1.f + Ec)), c);
                if (vOK) bw[wslot] = (_Float16)h;
            }
            if (xst) ((unsigned*)bw)[193 + 4 * col] = sXu[((s + 1) & (SEQ - 1)) * NB + col];
            asm volatile("s_waitcnt lgkmcnt(0)" ::: "memory");
            if (lane == 0) atomicAdd(&sCnt[0], 1u);
        }
    } else {
        // ---- L1 group: A = Wih1 over h1 + Whh1 over h2, 2 tiles ----
        f16x8 aI[2][2], aH[2][2];
        #pragma unroll
        for (int tt = 0; tt < 2; ++tt) {
            const int  m    = tt ? T1 : T0;
            const int  jr   = m * 4 + (nn >> 2);
            const int  gate = nn & 3;
            const bool rv   = (jr < H);
            const int  lrow = gate * H + jr;
            const float rsc = (gate == 2) ? -K2 : -K1;
            #pragma unroll
            for (int q = 0; q < 2; ++q) {
                #pragma unroll
                for (int j = 0; j < 8; ++j) {
                    const int k = q * 32 + quad * 8 + j;
                    const bool kv = rv && (k < 50);
                    aI[tt][q][j] = kv ? (_Float16)(rsc * Wih1[lrow * H + k]) : (_Float16)0.f;
                    aH[tt][q][j] = kv ? (_Float16)(rsc * Whh1[lrow * H + k]) : (_Float16)0.f;
                }
            }
        }
        float c = 0.f;
        #pragma unroll 1
        for (int p = 0; p < SEQ; ++p) {
            waitge(vc1, 7u * (unsigned)p);
            waitge(vc0, 7u * (unsigned)(p + 1));
            const _Float16* br = sRing[p & (D - 1)];
            const _Float16* hr = sH2[p & 1];
            _Float16*       hw = sH2[(p + 1) & 1];
            const f16x8 q0 = *(const f16x8*)&br[rbase];
            const f16x8 q1 = *(const f16x8*)&br[256 + rbase];
            const f16x8 r0 = *(const f16x8*)&hr[rbase];
            const f16x8 r1 = *(const f16x8*)&hr[256 + rbase];
            f32x4 gAa = biasA, gBa = biasB;
            gAa = __builtin_amdgcn_mfma_f32_16x16x32_f16(aI[0][0], q0, gAa, 0, 0, 0);
            gAa = __builtin_amdgcn_mfma_f32_16x16x32_f16(aI[0][1], q1, gAa, 0, 0, 0);
            gBa = __builtin_amdgcn_mfma_f32_16x16x32_f16(aI[1][0], q0, gBa, 0, 0, 0);
            gBa = __builtin_amdgcn_mfma_f32_16x16x32_f16(aI[1][1], q1, gBa, 0, 0, 0);
            f32x4 gAb = {0,0,0,0}, gBb = {0,0,0,0};
            gAb = __builtin_amdgcn_mfma_f32_16x16x32_f16(aH[0][0], r0, gAb, 0, 0, 0);
            gAb = __builtin_amdgcn_mfma_f32_16x16x32_f16(aH[0][1], r1, gAb, 0, 0, 0);
            gBb = __builtin_amdgcn_mfma_f32_16x16x32_f16(aH[1][0], r0, gBb, 0, 0, 0);
            gBb = __builtin_amdgcn_mfma_f32_16x16x32_f16(aH[1][1], r1, gBb, 0, 0, 0);
            float g[4];
            #pragma unroll
            for (int r = 0; r < 4; ++r)
                g[r] = selT ? (gBa[r] + gBb[r]) : (gAa[r] + gAb[r]);
            {   // act
                float Ei = fexp2(g[0]);
                float Ef = fexp2(g[1]);
                float Eg = fexp2(-fabsf(g[2]));
                float Eo = fexp2(g[3]);
                float P  = (1.f + Ei) * (1.f + Eg);
                float F  = 1.f + Ef;
                float R  = frcp(P * F);
                float tn = copysignf((1.f - Eg) * F, -g[2]);
                c = fmaf(c, P, tn) * R;
                float Ec = fexp2(-fabsf(K2 * c));
                float h  = copysignf((1.f - Ec) * frcp((1.f + Eo) * (1.f + Ec)), c);
                if (vOK) {
                    if (p == SEQ - 1) sH2f[jjS * NB + col] = h;
                    else              hw[wslot] = (_Float16)h;
                }
            }
            asm volatile("s_waitcnt lgkmcnt(0)" ::: "memory");
            if (lane == 0) atomicAdd(&sCnt[1], 1u);
        }
    }

    __syncthreads();
    // ---- FC epilogue: out[b] = fcW . h2_last[b] + fcb ----
    if (t < NB) {
        float sum = fcb[0];
        #pragma unroll
        for (int jx = 0; jx < H; ++jx) sum += fcW[jx] * sH2f[jx * NB + t];
        out[bbase + t] = sum;
    }
}

extern "C" void kernel_launch(void* const* d_in, const int* in_sizes, int n_in,
                              void* d_out, int out_size, void* d_ws, size_t ws_size,
                              hipStream_t stream)
{
    const float* x    = (const float*)d_in[0];
    const float* Wih0 = (const float*)d_in[1];
    const float* Whh0 = (const float*)d_in[2];
    const float* bih0 = (const float*)d_in[3];
    const float* bhh0 = (const float*)d_in[4];
    const float* Wih1 = (const float*)d_in[5];
    const float* Whh1 = (const float*)d_in[6];
    const float* bih1 = (const float*)d_in[7];
    const float* bhh1 = (const float*)d_in[8];
    const float* fcW  = (const float*)d_in[9];
    const float* fcb  = (const float*)d_in[10];

    lstm2_pc<<<BATCH / NB, NT, 0, stream>>>(
        x, Wih0, Whh0, bih0, bhh0, Wih1, Whh1, bih1, bhh1, fcW, fcb,
        (float*)d_out);
}

// Round 12
// 314.128 us; speedup vs baseline: 1.2361x; 1.2361x over previous
//
#include <hip/hip_runtime.h>

typedef _Float16 f16x8 __attribute__((ext_vector_type(8)));
typedef float    f32x4 __attribute__((ext_vector_type(4)));

constexpr int BATCH = 2048;
constexpr int SEQ   = 512;
constexpr int H     = 50;
constexpr int NB    = 8;     // batch per block -> 256 blocks = 1 per CU
constexpr int NT    = 896;   // 14 waves: 7 L0-role + 7 L1-role
constexpr int PSZ   = 1024;  // compact panel halfs per buffer (2 KB)

__device__ __forceinline__ float fexp2(float x) { return __builtin_amdgcn_exp2f(x); }
__device__ __forceinline__ float frcp(float x)  { return __builtin_amdgcn_rcpf(x); }
__device__ __forceinline__ _Float16 f16hi(float w) { return (_Float16)w; }
__device__ __forceinline__ _Float16 f16lo(float w) {
    _Float16 h = (_Float16)w; return (_Float16)(w - (float)h);
}
// compact B-panel address (halfs) for value (k, c), k<128, c<8 (single copy)
__device__ __forceinline__ int caddr(int k, int c) {
    return ((k >> 3) * 64) + c * 8 + (k & 7);
}
union H2U { unsigned u; _Float16 h[2]; };

constexpr float K1 = 1.4426950408889634f;   // log2(e)
constexpr float K2 = 2.8853900817779268f;   // 2*log2(e)

// === r19: barrier-synced role-split on the r17 substrate ===
// r18 falsified LDS-counter sync (~400cy/step vs s_barrier ~100), NOT role-
// splitting. r13's role-split lost for baggage reasons (2-step lag+prefetch,
// dual-acc+select, 22M conflicts). This is the clean version:
//   waves 0-6  (L0): h1(s) only. 2 tiles/wave {2w,2w+1} (w6:{12,13-dead}),
//     2 ds_read (chunks 0,1) + 4 MFMA + act(64 cells: selT=nn>>3 picks tile,
//     col=nn&7) + 1 h1 write. A = prescaled Whh0 + x hi/lo rows 50/51.
//   waves 7-13 (L1): h2(s-1) only (1-step lag, exactly as r17's hi-lanes):
//     4 ds_read + 8 MFMA (per tile: Wih1 2-chain over h1 + Whh1 2-chain
//     over h2, joined) + act + 1 h2 write. Same double-buffer parity as r17:
//     body s reads sB[s&1]={h1(s-1),x(s),h2(s-2)}, writes sB[(s+1)&1]=
//     {h1(s),x(s+1),h2(s-1)}.
// Per CU-step: reads 52->42, MFMA 78->84, act chains unchanged (full lane
// density, 1 chain/lane). Each SIMD hosts {2 L0, 2 L1} waves -> phase
// diversity without duplicated act issue. ONE s_barrier/step, reached by
// all 14 waves exactly once per body (wave-uniform branches only).
// x staged by wave 6's dead-tile lanes (quad0, nn>=8). Act math identical
// to r17 (prescaled gates, merged rcp) -> absmax unchanged.

__global__ __launch_bounds__(NT, 3) void lstm2_rs(
    const float* __restrict__ x,
    const float* __restrict__ Wih0, const float* __restrict__ Whh0,
    const float* __restrict__ bih0, const float* __restrict__ bhh0,
    const float* __restrict__ Wih1, const float* __restrict__ Whh1,
    const float* __restrict__ bih1, const float* __restrict__ bhh1,
    const float* __restrict__ fcW,  const float* __restrict__ fcb,
    float* __restrict__ out)
{
    __shared__ _Float16 sB[2][PSZ];     // double-buffered compact panel, 4 KB
    __shared__ unsigned sXu[SEQ * NB];  // pre-split x (hi,lo), 16 KB
    __shared__ float    sH2f[H * NB];   // final h2

    const int t    = threadIdx.x;
    const int wave = t >> 6, lane = t & 63;
    const int quad = lane >> 4, nn = lane & 15;
    const int bbase = blockIdx.x * NB;

    // zero both panels (h(-1)=0 init; rows k in [52,64),[114,128) stay 0)
    for (int i = t; i < 2 * PSZ; i += NT) ((_Float16*)sB)[i] = (_Float16)0.f;

    // pre-stage ALL x as packed f16 hi/lo pairs (coalesced along s)
    for (int i = t; i < NB * SEQ; i += NT) {
        const int b = i >> 9, s = i & (SEQ - 1);
        const float xv = x[(bbase + b) * SEQ + s];
        H2U p; p.h[0] = f16hi(xv); p.h[1] = f16lo(xv);
        sXu[s * NB + b] = p.u;
    }

    const bool isL1 = (wave >= 7);
    const int  wv   = isL1 ? wave - 7 : wave;
    const int  T0   = (wv < 6) ? 2 * wv     : 12;
    const int  T1   = (wv < 6) ? 2 * wv + 1 : 13;   // 13 = dead tile
    const int  selT = nn >> 3;              // lane's act tile: 0->T0, 1->T1
    const int  col  = nn & 7;               // batch
    const int  jjS  = (selT ? T1 : T0) * 4 + quad;
    const bool vOK  = (jjS < H);

    // ---- constant A-fragments (PRESCALED), per role ----
    f16x8 aA[2][2];            // L0: Whh0 (k<50) + x hi/lo rows 50/51
    f16x8 aI[2][2], aH[2][2];  // L1: Wih1 over h1, Whh1 over h2
    #pragma unroll
    for (int tt = 0; tt < 2; ++tt) {
        const int  m    = tt ? T1 : T0;
        const int  jr   = m * 4 + (nn >> 2);
        const int  gate = nn & 3;
        const bool rv   = (jr < H);
        const int  lrow = gate * H + jr;
        const float rsc = (gate == 2) ? -K2 : -K1;
        #pragma unroll
        for (int q = 0; q < 2; ++q) {
            #pragma unroll
            for (int j = 0; j < 8; ++j) {
                const int k = q * 32 + quad * 8 + j;
                _Float16 vA = (_Float16)0.f, vI = (_Float16)0.f, vH = (_Float16)0.f;
                if (rv) {
                    if (!isL1) {
                        if      (k < 50)  vA = (_Float16)(rsc * Whh0[lrow * H + k]);
                        else if (k == 50) vA = f16hi(rsc * Wih0[lrow]);
                        else if (k == 51) vA = f16lo(rsc * Wih0[lrow]);
                    } else if (k < 50) {
                        vI = (_Float16)(rsc * Wih1[lrow * H + k]);
                        vH = (_Float16)(rsc * Whh1[lrow * H + k]);
                    }
                }
                aA[tt][q][j] = vA; aI[tt][q][j] = vI; aH[tt][q][j] = vH;
            }
        }
    }
    f32x4 biasA = {0,0,0,0}, biasB = {0,0,0,0};
    {
        const float* bi = isL1 ? bih1 : bih0;
        const float* bh = isL1 ? bhh1 : bhh0;
        const int jqA = T0 * 4 + quad, jqB = T1 * 4 + quad;
        #pragma unroll
        for (int r = 0; r < 4; ++r) {
            const float sc = (r == 2) ? -K2 : -K1;
            biasA[r] = (jqA < H) ? sc * (bi[r * H + jqA] + bh[r * H + jqA]) : 0.f;
            biasB[r] = (jqB < H) ? sc * (bi[r * H + jqB] + bh[r * H + jqB]) : 0.f;
        }
    }

    const int rb0 = quad * 64 + col * 8;    // chunk bases (broadcast across nn/nn+8)
    const int rb1 = 256 + rb0, rb2 = 512 + rb0, rb3 = 768 + rb0;
    const int wslot = caddr((isL1 ? 64 : 0) + (vOK ? jjS : 0), col);
    const bool xst  = (!isL1) && (wv == 6) && (quad == 0) && (selT == 1);  // 8 lanes
    float c = 0.f;

    __syncthreads();
    if (t < NB)                              // x(0), rows 50/51 of panel 0
        ((unsigned*)sB[0])[193 + 4 * t] = sXu[t];
    __syncthreads();

    auto act = [&](float g0, float g1, float g2, float g3) -> float {
        float Ei = fexp2(g0);                    // e^{-i}
        float Ef = fexp2(g1);                    // e^{-f}
        float Eg = fexp2(-fabsf(g2));            // e^{-2|g~|}
        float Eo = fexp2(g3);                    // e^{-o}
        float P  = (1.f + Ei) * (1.f + Eg);
        float F  = 1.f + Ef;
        float R  = frcp(P * F);
        float tn = copysignf((1.f - Eg) * F, -g2);
        c = fmaf(c, P, tn) * R;
        float Ec = fexp2(-fabsf(K2 * c));
        return copysignf((1.f - Ec) * frcp((1.f + Eo) * (1.f + Ec)), c);
    };

    auto body = [&](int s, const _Float16* __restrict__ br,
                    _Float16* __restrict__ bw,
                    bool doL0, bool doL1, bool last) {
        if (!isL1) {
            if (doL0) {
                const f16x8 q0 = *(const f16x8*)&br[rb0];
                const f16x8 q1 = *(const f16x8*)&br[rb1];
                f32x4 gA = biasA;
                gA = __builtin_amdgcn_mfma_f32_16x16x32_f16(aA[0][0], q0, gA, 0, 0, 0);
                gA = __builtin_amdgcn_mfma_f32_16x16x32_f16(aA[0][1], q1, gA, 0, 0, 0);
                f32x4 gB = biasB;
                gB = __builtin_amdgcn_mfma_f32_16x16x32_f16(aA[1][0], q0, gB, 0, 0, 0);
                gB = __builtin_amdgcn_mfma_f32_16x16x32_f16(aA[1][1], q1, gB, 0, 0, 0);
                float h = act(selT ? gB[0] : gA[0], selT ? gB[1] : gA[1],
                              selT ? gB[2] : gA[2], selT ? gB[3] : gA[3]);
                if (vOK) bw[wslot] = (_Float16)h;    // h1(s)
            }
            if (xst)                                 // x(s+1) -> write panel
                ((unsigned*)bw)[193 + 4 * col] = sXu[((s + 1) & (SEQ - 1)) * NB + col];
        } else {
            if (doL1) {
                const f16x8 q0 = *(const f16x8*)&br[rb0];
                const f16x8 q1 = *(const f16x8*)&br[rb1];
                const f16x8 q2 = *(const f16x8*)&br[rb2];
                const f16x8 q3 = *(const f16x8*)&br[rb3];
                f32x4 gAa = biasA;
                gAa = __builtin_amdgcn_mfma_f32_16x16x32_f16(aI[0][0], q0, gAa, 0, 0, 0);
                gAa = __builtin_amdgcn_mfma_f32_16x16x32_f16(aI[0][1], q1, gAa, 0, 0, 0);
                f32x4 gAb = {0,0,0,0};
                gAb = __builtin_amdgcn_mfma_f32_16x16x32_f16(aH[0][0], q2, gAb, 0, 0, 0);
                gAb = __builtin_amdgcn_mfma_f32_16x16x32_f16(aH[0][1], q3, gAb, 0, 0, 0);
                f32x4 gBa = biasB;
                gBa = __builtin_amdgcn_mfma_f32_16x16x32_f16(aI[1][0], q0, gBa, 0, 0, 0);
                gBa = __builtin_amdgcn_mfma_f32_16x16x32_f16(aI[1][1], q1, gBa, 0, 0, 0);
                f32x4 gBb = {0,0,0,0};
                gBb = __builtin_amdgcn_mfma_f32_16x16x32_f16(aH[1][0], q2, gBb, 0, 0, 0);
                gBb = __builtin_amdgcn_mfma_f32_16x16x32_f16(aH[1][1], q3, gBb, 0, 0, 0);
                float g[4];
                #pragma unroll
                for (int r = 0; r < 4; ++r)
                    g[r] = selT ? (gBa[r] + gBb[r]) : (gAa[r] + gAb[r]);
                float h = act(g[0], g[1], g[2], g[3]);
                if (vOK) {
                    if (last) sH2f[jjS * NB + col] = h;   // h2(511) for the FC
                    else      bw[wslot] = (_Float16)h;    // h2(s-1)
                }
            }
        }
        __syncthreads();   // the ONLY barrier per step (all 14 waves, always)
    };

    body(0, sB[0], sB[1], true, false, false);
    #pragma unroll 1
    for (int i = 0; i < 255; ++i) {
        body(2 * i + 1, sB[1], sB[0], true, true, false);
        body(2 * i + 2, sB[0], sB[1], true, true, false);
    }
    body(511, sB[1], sB[0], true, true, false);
    body(512, sB[0], sB[1], false, true, true);

    // ---- FC epilogue: out[b] = fcW . h2_last[b] + fcb ----
    if (t < NB) {
        float sum = fcb[0];
        #pragma unroll
        for (int jx = 0; jx < H; ++jx) sum += fcW[jx] * sH2f[jx * NB + t];
        out[bbase + t] = sum;
    }
}

extern "C" void kernel_launch(void* const* d_in, const int* in_sizes, int n_in,
                              void* d_out, int out_size, void* d_ws, size_t ws_size,
                              hipStream_t stream)
{
    const float* x    = (const float*)d_in[0];
    const float* Wih0 = (const float*)d_in[1];
    const float* Whh0 = (const float*)d_in[2];
    const float* bih0 = (const float*)d_in[3];
    const float* bhh0 = (const float*)d_in[4];
    const float* Wih1 = (const float*)d_in[5];
    const float* Whh1 = (const float*)d_in[6];
    const float* bih1 = (const float*)d_in[7];
    const float* bhh1 = (const float*)d_in[8];
    const float* fcW  = (const float*)d_in[9];
    const float* fcb  = (const float*)d_in[10];

    lstm2_rs<<<BATCH / NB, NT, 0, stream>>>(
        x, Wih0, Whh0, bih0, bhh0, Wih1, Whh1, bih1, bhh1, fcW, fcb,
        (float*)d_out);
}